// Round 10
// baseline (977.609 us; speedup 1.0000x reference)
//
#include <hip/hip_runtime.h>

// GCN layer: out = A_coo @ (X @ W) + b
// N=100000 nodes, E=3200000 edges, D_IN=D_OUT=256.
//
// R13: sweep with throughput-correct structure.
// Traffic model proven (FETCH 764 random -> 275MB best sweep); all sweep
// failures were structural: R10 spill (acc array), R11 AGPR overflow
// (192 acc regs, 1 wave/SIMD), R12 too fine (G=16: 1.5 generations,
// 16-edge segments, broadcast eP loads -> latency-serial, FETCH 443MB).
// Fix: G=32 (dst>>5/&31), NGRP=3125 (~single resident generation),
// NB=16 (64-edge segments), launch_bounds(256,3) (165 regs, no spill),
// lane-coalesced eP staging + __shfl extraction (1 load per 64 edges),
// 4-deep row-load batches between wave-uniform 32-case switch applies.

typedef __bf16 bf16;
typedef bf16 bf16x4 __attribute__((ext_vector_type(4)));
typedef bf16 bf16x8 __attribute__((ext_vector_type(8)));
typedef float f32x4 __attribute__((ext_vector_type(4)));
typedef int i32x2 __attribute__((ext_vector_type(2)));

#define D_DIM 256
#define NB 16          // src buckets (3.2MB of S each)
#define G 32           // dst nodes per wavegroup (power of 2)
#define NGRP 3125      // wavegroups = 100000/32 (~single generation)

__device__ __forceinline__ int bucket_of(unsigned s, unsigned magic) {
    unsigned b = (unsigned)(((unsigned long long)s * magic) >> 32);
    return b > (NB - 1) ? (NB - 1) : (int)b;
}

// ---- 1) pack W[256][256] fp32 -> bf16 MFMA B-fragment layout ----
__global__ void pack_w(const float* __restrict__ W, bf16* __restrict__ Wf) {
    int lane = threadIdx.x;           // 64
    int blk  = blockIdx.x;            // 128 = 8 kt * 16 nt
    int kt = blk >> 4, nt = blk & 15;
    int t = lane & 15, q = lane >> 4;
    int krow = kt * 32 + q * 8;
    int col  = nt * 16 + t;
    bf16x8 v;
#pragma unroll
    for (int j = 0; j < 8; ++j)
        v[j] = (bf16)W[(size_t)(krow + j) * D_DIM + col];
    ((bf16x8*)Wf)[(size_t)blk * 64 + lane] = v;
}

// ---- 2) GEMM: support = X @ W (bf16 out). One wave = 16 rows x 256 cols ----
__global__ void gemm_xw(const float* __restrict__ X, const bf16* __restrict__ Wf,
                        bf16* __restrict__ S, int N) {
    int wid  = blockIdx.x * 4 + (threadIdx.x >> 6);
    int base = wid * 16;
    if (base >= N) return;
    int lane = threadIdx.x & 63;
    int t = lane & 15, q = lane >> 4;

    const float* xrow = X + (size_t)(base + t) * D_DIM + q * 8;
    const bf16x8* wf = (const bf16x8*)Wf;

    f32x4 acc[16];
#pragma unroll
    for (int i = 0; i < 16; ++i) acc[i] = (f32x4){0.f, 0.f, 0.f, 0.f};

#pragma unroll
    for (int kt = 0; kt < 8; ++kt) {
        f32x4 x0 = *(const f32x4*)(xrow + kt * 32);
        f32x4 x1 = *(const f32x4*)(xrow + kt * 32 + 4);
        bf16x8 a;
        a[0] = (bf16)x0[0]; a[1] = (bf16)x0[1]; a[2] = (bf16)x0[2]; a[3] = (bf16)x0[3];
        a[4] = (bf16)x1[0]; a[5] = (bf16)x1[1]; a[6] = (bf16)x1[2]; a[7] = (bf16)x1[3];
#pragma unroll
        for (int nt = 0; nt < 16; ++nt) {
            bf16x8 bfr = wf[(size_t)(kt * 16 + nt) * 64 + lane];
            acc[nt] = __builtin_amdgcn_mfma_f32_16x16x32_bf16(a, bfr, acc[nt], 0, 0, 0);
        }
    }

#pragma unroll
    for (int nt = 0; nt < 16; ++nt) {
#pragma unroll
        for (int r = 0; r < 4; ++r) {
            S[(size_t)(base + q * 4 + r) * D_DIM + nt * 16 + t] = (bf16)acc[nt][r];
        }
    }
}

// ---- 3a) histogram + rank over NB*NGRP (bucket,group) keys. 8/thread ----
__global__ void rank4(const int* __restrict__ esrc, const int* __restrict__ edst,
                      int* __restrict__ cnt, int* __restrict__ erank, int E,
                      unsigned bmagic) {
    int gid  = blockIdx.x * blockDim.x + threadIdx.x;
    int base = gid * 8;
    if (base + 8 <= E) {
        int4 s0 = *(const int4*)(esrc + base);
        int4 s1 = *(const int4*)(esrc + base + 4);
        int4 d0 = *(const int4*)(edst + base);
        int4 d1 = *(const int4*)(edst + base + 4);
        int4 r0, r1;
        r0.x = atomicAdd(&cnt[bucket_of(s0.x, bmagic) * NGRP + (d0.x >> 5)], 1);
        r0.y = atomicAdd(&cnt[bucket_of(s0.y, bmagic) * NGRP + (d0.y >> 5)], 1);
        r0.z = atomicAdd(&cnt[bucket_of(s0.z, bmagic) * NGRP + (d0.z >> 5)], 1);
        r0.w = atomicAdd(&cnt[bucket_of(s0.w, bmagic) * NGRP + (d0.w >> 5)], 1);
        r1.x = atomicAdd(&cnt[bucket_of(s1.x, bmagic) * NGRP + (d1.x >> 5)], 1);
        r1.y = atomicAdd(&cnt[bucket_of(s1.y, bmagic) * NGRP + (d1.y >> 5)], 1);
        r1.z = atomicAdd(&cnt[bucket_of(s1.z, bmagic) * NGRP + (d1.z >> 5)], 1);
        r1.w = atomicAdd(&cnt[bucket_of(s1.w, bmagic) * NGRP + (d1.w >> 5)], 1);
        *(int4*)(erank + base)     = r0;
        *(int4*)(erank + base + 4) = r1;
    } else {
        for (int e = base; e < E; ++e)
            erank[e] = atomicAdd(
                &cnt[bucket_of(esrc[e], bmagic) * NGRP + (edst[e] >> 5)], 1);
    }
}

// ---- 3b) per-block exclusive scan (1024 elems/block) ----
__global__ void scan_block(const int* __restrict__ counts, int n,
                           int* __restrict__ local_ex, int* __restrict__ bsums) {
    __shared__ int lds[1024];
    int tid = threadIdx.x;
    int g = blockIdx.x * 1024 + tid;
    int v = (g < n) ? counts[g] : 0;
    lds[tid] = v;
    __syncthreads();
    for (int d = 1; d < 1024; d <<= 1) {
        int add = (tid >= d) ? lds[tid - d] : 0;
        __syncthreads();
        lds[tid] += add;
        __syncthreads();
    }
    if (g < n) local_ex[g] = lds[tid] - v;
    if (tid == 1023) bsums[blockIdx.x] = lds[tid];
}

// ---- 3c) scan of block sums (single block, nb <= 256) ----
__global__ void scan_sums(const int* __restrict__ bsums, int nb, int* __restrict__ bex) {
    __shared__ int lds[256];
    int tid = threadIdx.x;
    int v = (tid < nb) ? bsums[tid] : 0;
    lds[tid] = v;
    __syncthreads();
    for (int d = 1; d < 256; d <<= 1) {
        int add = (tid >= d) ? lds[tid - d] : 0;
        __syncthreads();
        lds[tid] += add;
        __syncthreads();
    }
    if (tid < nb) bex[tid] = lds[tid] - v;
}

// ---- 3d) add block base; also writes sentinel off[n] = E ----
__global__ void add_base(int* __restrict__ off, const int* __restrict__ bex,
                         int n, int E) {
    int g = blockIdx.x * 1024 + threadIdx.x;
    if (g < n) off[g] += bex[blockIdx.x];
    if (g == 0) off[n] = E;
}

// ---- 3e) scatter (ATOMIC-FREE): pos = off[key] + rank; payload packs dloc ----
__global__ void scatter4(const int* __restrict__ esrc, const int* __restrict__ edst,
                         const float* __restrict__ evals, const int* __restrict__ erank,
                         const int* __restrict__ off, i32x2* __restrict__ eP, int E,
                         unsigned bmagic) {
    int gid  = blockIdx.x * blockDim.x + threadIdx.x;
    int base = gid * 8;
    if (base + 8 <= E) {
        int4 s0 = *(const int4*)(esrc + base);
        int4 s1 = *(const int4*)(esrc + base + 4);
        int4 d0 = *(const int4*)(edst + base);
        int4 d1 = *(const int4*)(edst + base + 4);
        int4 r0 = *(const int4*)(erank + base);
        int4 r1 = *(const int4*)(erank + base + 4);
        float4 v0 = *(const float4*)(evals + base);
        float4 v1 = *(const float4*)(evals + base + 4);
        int ss[8] = {s0.x, s0.y, s0.z, s0.w, s1.x, s1.y, s1.z, s1.w};
        int dd[8] = {d0.x, d0.y, d0.z, d0.w, d1.x, d1.y, d1.z, d1.w};
        int rr[8] = {r0.x, r0.y, r0.z, r0.w, r1.x, r1.y, r1.z, r1.w};
        float vv[8] = {v0.x, v0.y, v0.z, v0.w, v1.x, v1.y, v1.z, v1.w};
#pragma unroll
        for (int j = 0; j < 8; ++j) {
            int wg = dd[j] >> 5;
            int dl = dd[j] & 31;
            int key = bucket_of(ss[j], bmagic) * NGRP + wg;
            int pos = off[key] + rr[j];
            eP[pos] = (i32x2){ss[j] | (dl << 20), __float_as_int(vv[j])};
        }
    } else {
        for (int e = base; e < E; ++e) {
            int wg = edst[e] >> 5;
            int dl = edst[e] & 31;
            int key = bucket_of(esrc[e], bmagic) * NGRP + wg;
            int pos = off[key] + erank[e];
            eP[pos] = (i32x2){esrc[e] | (dl << 20), __float_as_int(evals[e])};
        }
    }
}

// ---- 4) aggregate7: 3125 wavegroups (~all resident) sweep 16 src-buckets.
// Wave owns G=32 nodes (32 named f32x4); eP staged via lane-coalesced load
// + __shfl; S-row gathers batched 4-deep; wave-uniform 32-case jump table.
#define FOR32(M) M(0) M(1) M(2) M(3) M(4) M(5) M(6) M(7) M(8) M(9) M(10) \
    M(11) M(12) M(13) M(14) M(15) M(16) M(17) M(18) M(19) M(20) M(21)    \
    M(22) M(23) M(24) M(25) M(26) M(27) M(28) M(29) M(30) M(31)

#define DECLA(i) f32x4 A##i = bias;
#define CASEA(i) case i: A##i[0]+=f0; A##i[1]+=f1; A##i[2]+=f2; A##i[3]+=f3; break;
#define STOREA(i) __builtin_nontemporal_store(A##i,                              \
        (f32x4*)out + (size_t)(wbase + i) * 64 + lane);

#define APPLY(KEY, WT, V) {                                                      \
    float wt = __int_as_float(WT);                                               \
    float f0 = wt * (float)(V)[0], f1 = wt * (float)(V)[1],                      \
          f2 = wt * (float)(V)[2], f3 = wt * (float)(V)[3];                      \
    switch (((unsigned)(KEY)) >> 20) { FOR32(CASEA) } }

__global__ void __launch_bounds__(256, 3) aggregate7(
        const bf16* __restrict__ S, const int* __restrict__ off4,
        const i32x2* __restrict__ eP, const float* __restrict__ b,
        float* __restrict__ out, int N) {
    int wid  = threadIdx.x >> 6;
    int lane = threadIdx.x & 63;
    int w    = blockIdx.x * 4 + wid;        // wavegroup id
    if (w >= NGRP) return;

    const f32x4 bias = ((const f32x4*)b)[lane];
    FOR32(DECLA)

    for (int k = 0; k < NB; ++k) {
        i32x2 se = *(const i32x2*)(off4 + k * NGRP + w);   // [start, end)
        int s = se[0], t = se[1];
        for (int base = s; base < t; base += 64) {
            int m = t - base; if (m > 64) m = 64;
            int idx = base + lane; if (idx >= t) idx = t - 1;
            i32x2 P = eP[idx];                 // one coalesced load / 64 edges
            int e = 0;
            for (; e + 4 <= m; e += 4) {
                int k0 = __shfl(P[0], e + 0), w0 = __shfl(P[1], e + 0);
                int k1 = __shfl(P[0], e + 1), w1 = __shfl(P[1], e + 1);
                int k2 = __shfl(P[0], e + 2), w2 = __shfl(P[1], e + 2);
                int k3 = __shfl(P[0], e + 3), w3 = __shfl(P[1], e + 3);
                bf16x4 v0 = *((const bf16x4*)(S + (size_t)(k0 & 0xFFFFF) * D_DIM) + lane);
                bf16x4 v1 = *((const bf16x4*)(S + (size_t)(k1 & 0xFFFFF) * D_DIM) + lane);
                bf16x4 v2 = *((const bf16x4*)(S + (size_t)(k2 & 0xFFFFF) * D_DIM) + lane);
                bf16x4 v3 = *((const bf16x4*)(S + (size_t)(k3 & 0xFFFFF) * D_DIM) + lane);
                APPLY(k0, w0, v0) APPLY(k1, w1, v1)
                APPLY(k2, w2, v2) APPLY(k3, w3, v3)
            }
            for (; e < m; ++e) {
                int kk = __shfl(P[0], e), ww = __shfl(P[1], e);
                bf16x4 v = *((const bf16x4*)(S + (size_t)(kk & 0xFFFFF) * D_DIM) + lane);
                APPLY(kk, ww, v)
            }
        }
    }

    int wbase = w * G;                      // 3125*32 = 100000 exactly
    FOR32(STOREA)
}

extern "C" void kernel_launch(void* const* d_in, const int* in_sizes, int n_in,
                              void* d_out, int out_size, void* d_ws, size_t ws_size,
                              hipStream_t stream) {
    const float* X     = (const float*)d_in[0];
    const int*   esrc  = (const int*)d_in[1];
    const int*   edst  = (const int*)d_in[2];
    const float* evals = (const float*)d_in[3];
    const float* W     = (const float*)d_in[4];
    const float* bias  = (const float*)d_in[5];
    float* out = (float*)d_out;

    const int N = in_sizes[0] / D_DIM;   // 100000
    const int E = in_sizes[1];           // 3200000

    const int M2 = NB * NGRP;            // 50000 keys
    const unsigned bmagic = (unsigned)((((unsigned long long)NB << 32) + N - 1) / N);

    // workspace carve-up (256B aligned)
    auto alignup = [](size_t x) { return (x + 255) & ~(size_t)255; };
    char* ws = (char*)d_ws;
    size_t o = 0;
    bf16* S      = (bf16*)(ws + o); o = alignup(o + (size_t)N * D_DIM * sizeof(bf16));
    int* cnt4    = (int*)(ws + o);  o = alignup(o + (size_t)(M2 + 16) * sizeof(int));
    int* off4    = (int*)(ws + o);  o = alignup(o + (size_t)(M2 + 16) * sizeof(int));
    int* erank   = (int*)(ws + o);  o = alignup(o + (size_t)E * sizeof(int));
    int* bsums   = (int*)(ws + o);  o = alignup(o + 1024 * sizeof(int));
    int* bex     = (int*)(ws + o);  o = alignup(o + 1024 * sizeof(int));
    i32x2* eP    = (i32x2*)(ws + o); o = alignup(o + (size_t)E * sizeof(i32x2));
    bf16* Wf     = (bf16*)(ws + o); o = alignup(o + (size_t)D_DIM * D_DIM * sizeof(bf16));

    const int nwaves = (N + 15) / 16;              // gemm waves
    const int nb8    = ((E + 7) / 8 + 255) / 256;  // blocks for 8-edge kernels
    const int nbs    = (M2 + 1023) / 1024;         // 49 scan blocks (<=256)

    hipMemsetAsync(cnt4, 0, (size_t)(M2 + 16) * sizeof(int), stream);
    pack_w<<<128, 64, 0, stream>>>(W, Wf);
    gemm_xw<<<(nwaves + 3) / 4, 256, 0, stream>>>(X, Wf, S, N);
    rank4<<<nb8, 256, 0, stream>>>(esrc, edst, cnt4, erank, E, bmagic);
    scan_block<<<nbs, 1024, 0, stream>>>(cnt4, M2, off4, bsums);
    scan_sums<<<1, 256, 0, stream>>>(bsums, nbs, bex);
    add_base<<<nbs, 1024, 0, stream>>>(off4, bex, M2, E);
    scatter4<<<nb8, 256, 0, stream>>>(esrc, edst, evals, erank, off4, eP, E, bmagic);
    aggregate7<<<(NGRP + 3) / 4, 256, 0, stream>>>(S, off4, eP, bias, out, N);
}

// Round 11
// 631.488 us; speedup vs baseline: 1.5481x; 1.5481x over previous
//
#include <hip/hip_runtime.h>

// GCN layer: out = A_coo @ (X @ W) + b
// N=100000 nodes, E=3200000 edges, D_IN=D_OUT=256.
//
// R14: revert to R5 flat pipeline (664us proven; flat aggregate 231us) per
// the R13 kill-switch: four sweep variants (R10-R13) all lose more to the
// accumulator-state/occupancy/segment-size triangle than the proven traffic
// gain (FETCH 764->275MB) is worth. Attack the ~430us non-aggregate tail:
//  1. FUSE gemm_xw + rank_edges (independent chains; streams/events banned
//     under graph capture, so fuse: even blocks gemm, odd blocks rank).
//  2. DELETE add_base: fold bex[g>>10] into scatter + aggregate; counts
//     extended to N+1 so off[N]+bex[97]=E sentinel falls out of the scan.

typedef __bf16 bf16;
typedef bf16 bf16x4 __attribute__((ext_vector_type(4)));
typedef bf16 bf16x8 __attribute__((ext_vector_type(8)));
typedef float f32x4 __attribute__((ext_vector_type(4)));
typedef int i32x2 __attribute__((ext_vector_type(2)));
typedef int i32x4 __attribute__((ext_vector_type(4)));

#define D_DIM 256

// ---- 1) pack W[256][256] fp32 -> bf16 MFMA B-fragment layout ----
__global__ void pack_w(const float* __restrict__ W, bf16* __restrict__ Wf) {
    int lane = threadIdx.x;           // 64
    int blk  = blockIdx.x;            // 128 = 8 kt * 16 nt
    int kt = blk >> 4, nt = blk & 15;
    int t = lane & 15, q = lane >> 4;
    int krow = kt * 32 + q * 8;
    int col  = nt * 16 + t;
    bf16x8 v;
#pragma unroll
    for (int j = 0; j < 8; ++j)
        v[j] = (bf16)W[(size_t)(krow + j) * D_DIM + col];
    ((bf16x8*)Wf)[(size_t)blk * 64 + lane] = v;
}

// ---- 2) FUSED: even blocks run GEMM (support = X@W), odd blocks run
//         histogram+rank (rank[e] = old count of dst). Bodies identical to
//         the proven standalone kernels; only block-id mapping changed.
__global__ void gemm_rank(const float* __restrict__ X, const bf16* __restrict__ Wf,
                          bf16* __restrict__ S, int N,
                          const int* __restrict__ edst, int* __restrict__ counts,
                          int* __restrict__ erank, int E) {
    if (blockIdx.x & 1) {
        // ---- rank body (8 edges/thread) ----
        int gid  = (blockIdx.x >> 1) * blockDim.x + threadIdx.x;
        int base = gid * 8;
        if (base + 8 <= E) {
            int4 d0 = *(const int4*)(edst + base);
            int4 d1 = *(const int4*)(edst + base + 4);
            int4 r0, r1;
            r0.x = atomicAdd(&counts[d0.x], 1);
            r0.y = atomicAdd(&counts[d0.y], 1);
            r0.z = atomicAdd(&counts[d0.z], 1);
            r0.w = atomicAdd(&counts[d0.w], 1);
            r1.x = atomicAdd(&counts[d1.x], 1);
            r1.y = atomicAdd(&counts[d1.y], 1);
            r1.z = atomicAdd(&counts[d1.z], 1);
            r1.w = atomicAdd(&counts[d1.w], 1);
            *(int4*)(erank + base)     = r0;
            *(int4*)(erank + base + 4) = r1;
        } else {
            for (int e = base; e < E; ++e)
                erank[e] = atomicAdd(&counts[edst[e]], 1);
        }
        return;
    }
    // ---- gemm body: one wave = 16 rows x 256 cols ----
    int wid  = (blockIdx.x >> 1) * 4 + (threadIdx.x >> 6);
    int base = wid * 16;
    if (base >= N) return;
    int lane = threadIdx.x & 63;
    int t = lane & 15, q = lane >> 4;

    const float* xrow = X + (size_t)(base + t) * D_DIM + q * 8;
    const bf16x8* wf = (const bf16x8*)Wf;

    f32x4 acc[16];
#pragma unroll
    for (int i = 0; i < 16; ++i) acc[i] = (f32x4){0.f, 0.f, 0.f, 0.f};

#pragma unroll
    for (int kt = 0; kt < 8; ++kt) {
        f32x4 x0 = *(const f32x4*)(xrow + kt * 32);
        f32x4 x1 = *(const f32x4*)(xrow + kt * 32 + 4);
        bf16x8 a;
        a[0] = (bf16)x0[0]; a[1] = (bf16)x0[1]; a[2] = (bf16)x0[2]; a[3] = (bf16)x0[3];
        a[4] = (bf16)x1[0]; a[5] = (bf16)x1[1]; a[6] = (bf16)x1[2]; a[7] = (bf16)x1[3];
#pragma unroll
        for (int nt = 0; nt < 16; ++nt) {
            bf16x8 bfr = wf[(size_t)(kt * 16 + nt) * 64 + lane];
            acc[nt] = __builtin_amdgcn_mfma_f32_16x16x32_bf16(a, bfr, acc[nt], 0, 0, 0);
        }
    }

#pragma unroll
    for (int nt = 0; nt < 16; ++nt) {
#pragma unroll
        for (int r = 0; r < 4; ++r) {
            S[(size_t)(base + q * 4 + r) * D_DIM + nt * 16 + t] = (bf16)acc[nt][r];
        }
    }
}

// ---- 3b) per-block exclusive scan (1024 elems/block) over N+1 counts ----
__global__ void scan_block(const int* __restrict__ counts, int n,
                           int* __restrict__ local_ex, int* __restrict__ bsums) {
    __shared__ int lds[1024];
    int tid = threadIdx.x;
    int g = blockIdx.x * 1024 + tid;
    int v = (g < n) ? counts[g] : 0;
    lds[tid] = v;
    __syncthreads();
    for (int d = 1; d < 1024; d <<= 1) {
        int add = (tid >= d) ? lds[tid - d] : 0;
        __syncthreads();
        lds[tid] += add;
        __syncthreads();
    }
    if (g < n) local_ex[g] = lds[tid] - v;
    if (tid == 1023) bsums[blockIdx.x] = lds[tid];
}

// ---- 3c) scan of block sums (single block, nb <= 128) ----
__global__ void scan_sums(const int* __restrict__ bsums, int nb, int* __restrict__ bex) {
    __shared__ int lds[128];
    int tid = threadIdx.x;
    int v = (tid < nb) ? bsums[tid] : 0;
    lds[tid] = v;
    __syncthreads();
    for (int d = 1; d < 128; d <<= 1) {
        int add = (tid >= d) ? lds[tid - d] : 0;
        __syncthreads();
        lds[tid] += add;
        __syncthreads();
    }
    if (tid < nb) bex[tid] = lds[tid] - v;
}

// ---- 3e) scatter (ATOMIC-FREE): pos = off[d] + bex[d>>10] + rank ----
__global__ void scatter_edges(const int* __restrict__ esrc, const int* __restrict__ edst,
                              const float* __restrict__ evals, const int* __restrict__ erank,
                              const int* __restrict__ off, const int* __restrict__ bex,
                              i32x2* __restrict__ eP, int E) {
    int gid  = blockIdx.x * blockDim.x + threadIdx.x;
    int base = gid * 8;
    if (base + 8 <= E) {
        int4 s0 = *(const int4*)(esrc + base);
        int4 s1 = *(const int4*)(esrc + base + 4);
        int4 d0 = *(const int4*)(edst + base);
        int4 d1 = *(const int4*)(edst + base + 4);
        int4 r0 = *(const int4*)(erank + base);
        int4 r1 = *(const int4*)(erank + base + 4);
        float4 v0 = *(const float4*)(evals + base);
        float4 v1 = *(const float4*)(evals + base + 4);
        int p0 = off[d0.x] + bex[d0.x >> 10] + r0.x;
        int p1 = off[d0.y] + bex[d0.y >> 10] + r0.y;
        int p2 = off[d0.z] + bex[d0.z >> 10] + r0.z;
        int p3 = off[d0.w] + bex[d0.w >> 10] + r0.w;
        int p4 = off[d1.x] + bex[d1.x >> 10] + r1.x;
        int p5 = off[d1.y] + bex[d1.y >> 10] + r1.y;
        int p6 = off[d1.z] + bex[d1.z >> 10] + r1.z;
        int p7 = off[d1.w] + bex[d1.w >> 10] + r1.w;
        eP[p0] = (i32x2){s0.x, __float_as_int(v0.x)};
        eP[p1] = (i32x2){s0.y, __float_as_int(v0.y)};
        eP[p2] = (i32x2){s0.z, __float_as_int(v0.z)};
        eP[p3] = (i32x2){s0.w, __float_as_int(v0.w)};
        eP[p4] = (i32x2){s1.x, __float_as_int(v1.x)};
        eP[p5] = (i32x2){s1.y, __float_as_int(v1.y)};
        eP[p6] = (i32x2){s1.z, __float_as_int(v1.z)};
        eP[p7] = (i32x2){s1.w, __float_as_int(v1.w)};
    } else {
        for (int e = base; e < E; ++e) {
            int d = edst[e];
            eP[off[d] + bex[d >> 10] + erank[e]] =
                (i32x2){esrc[e], __float_as_int(evals[e])};
        }
    }
}

// ---- 4) aggregate: one wave per node; lane owns cols [lane*4, lane*4+4) ----
// (proven R5 version, 230us; offsets now off[g]+bex[g>>10])
__global__ void __launch_bounds__(256) aggregate(
        const bf16* __restrict__ S, const int* __restrict__ off,
        const int* __restrict__ bex, const i32x2* __restrict__ eP,
        const float* __restrict__ b, float* __restrict__ out, int N) {
    int w = blockIdx.x * 4 + (threadIdx.x >> 6);
    if (w >= N) return;
    int lane = threadIdx.x & 63;

    f32x4 acc = ((const f32x4*)b)[lane];

    int e   = off[w]     + bex[w >> 10];
    int end = off[w + 1] + bex[(w + 1) >> 10];

    // main: 16 edges in flight
    for (; e + 16 <= end; e += 16) {
        i32x2 r[16];
#pragma unroll
        for (int j = 0; j < 16; ++j) r[j] = __builtin_nontemporal_load(&eP[e + j]);
        bf16x4 v[16];
#pragma unroll
        for (int j = 0; j < 16; ++j)
            v[j] = *((const bf16x4*)(S + (size_t)r[j][0] * D_DIM) + lane);
#pragma unroll
        for (int j = 0; j < 16; ++j) {
            float wt = __int_as_float(r[j][1]);
            acc[0] += wt * (float)v[j][0];
            acc[1] += wt * (float)v[j][1];
            acc[2] += wt * (float)v[j][2];
            acc[3] += wt * (float)v[j][3];
        }
    }
    // mid: 4 at a time
    for (; e + 4 <= end; e += 4) {
        i32x2 r[4];
#pragma unroll
        for (int j = 0; j < 4; ++j) r[j] = __builtin_nontemporal_load(&eP[e + j]);
        bf16x4 v[4];
#pragma unroll
        for (int j = 0; j < 4; ++j)
            v[j] = *((const bf16x4*)(S + (size_t)r[j][0] * D_DIM) + lane);
#pragma unroll
        for (int j = 0; j < 4; ++j) {
            float wt = __int_as_float(r[j][1]);
            acc[0] += wt * (float)v[j][0];
            acc[1] += wt * (float)v[j][1];
            acc[2] += wt * (float)v[j][2];
            acc[3] += wt * (float)v[j][3];
        }
    }
    for (; e < end; ++e) {
        i32x2 r = eP[e];
        float wt = __int_as_float(r[1]);
        bf16x4 v = *((const bf16x4*)(S + (size_t)r[0] * D_DIM) + lane);
        acc[0] += wt * (float)v[0];
        acc[1] += wt * (float)v[1];
        acc[2] += wt * (float)v[2];
        acc[3] += wt * (float)v[3];
    }
    __builtin_nontemporal_store(acc, (f32x4*)out + (size_t)w * 64 + lane);
}

extern "C" void kernel_launch(void* const* d_in, const int* in_sizes, int n_in,
                              void* d_out, int out_size, void* d_ws, size_t ws_size,
                              hipStream_t stream) {
    const float* X     = (const float*)d_in[0];
    const int*   esrc  = (const int*)d_in[1];
    const int*   edst  = (const int*)d_in[2];
    const float* evals = (const float*)d_in[3];
    const float* W     = (const float*)d_in[4];
    const float* bias  = (const float*)d_in[5];
    float* out = (float*)d_out;

    const int N = in_sizes[0] / D_DIM;   // 100000
    const int E = in_sizes[1];           // 3200000

    // workspace carve-up (256B aligned)
    auto alignup = [](size_t x) { return (x + 255) & ~(size_t)255; };
    char* ws = (char*)d_ws;
    size_t o = 0;
    bf16* S      = (bf16*)(ws + o); o = alignup(o + (size_t)N * D_DIM * sizeof(bf16));
    int* counts  = (int*)(ws + o);  o = alignup(o + (size_t)(N + 1) * sizeof(int));
    int* off     = (int*)(ws + o);  o = alignup(o + (size_t)(N + 1) * sizeof(int));
    int* erank   = (int*)(ws + o);  o = alignup(o + (size_t)E * sizeof(int));
    int* bsums   = (int*)(ws + o);  o = alignup(o + 1024 * sizeof(int));
    int* bex     = (int*)(ws + o);  o = alignup(o + 1024 * sizeof(int));
    i32x2* eP    = (i32x2*)(ws + o); o = alignup(o + (size_t)E * sizeof(i32x2));
    bf16* Wf     = (bf16*)(ws + o); o = alignup(o + (size_t)D_DIM * D_DIM * sizeof(bf16));

    const int nb = (N + 1 + 1023) / 1024;     // 98 scan blocks over N+1
    const int nwaves  = (N + 15) / 16;        // 6250 gemm waves
    const int ngemmb  = (nwaves + 3) / 4;     // 1563 gemm blocks
    const int nrankb  = ((E + 7) / 8 + 255) / 256;  // 1563 rank blocks
    // fused grid: even blocks gemm (1563), odd blocks rank (1563)
    const int nfused  = 2 * ((ngemmb > nrankb) ? ngemmb : nrankb);

    hipMemsetAsync(counts, 0, (size_t)(N + 1) * sizeof(int), stream);
    pack_w<<<128, 64, 0, stream>>>(W, Wf);
    gemm_rank<<<nfused, 256, 0, stream>>>(X, Wf, S, N, edst, counts, erank, E);
    scan_block<<<nb, 1024, 0, stream>>>(counts, N + 1, off, bsums);
    scan_sums<<<1, 128, 0, stream>>>(bsums, nb, bex);
    scatter_edges<<<nrankb, 256, 0, stream>>>(esrc, edst, evals, erank, off, bex, eP, E);
    aggregate<<<(N + 3) / 4, 256, 0, stream>>>(S, off, bex, eP, bias, out, N);
}